// Round 9
// baseline (246.617 us; speedup 1.0000x reference)
//
#include <hip/hip_runtime.h>
#include <hip/hip_bf16.h>

typedef __bf16 bf16x8 __attribute__((ext_vector_type(8)));
typedef float  f32x4  __attribute__((ext_vector_type(4)));
typedef float  f32x16 __attribute__((ext_vector_type(16)));
typedef int    i32x4  __attribute__((ext_vector_type(4)));

#define SEQ 4096
#define CIN 64
#define KBLK 64
#define KSPLIT 8
#define KCHUNK (SEQ / KSPLIT)          // 512 keys per block
#define NTC (KCHUNK / KBLK)            // 8 iters
#define LOG2E 1.44269504088896340736f

__device__ __forceinline__ void gll16(const void* g, void* l) {
    __builtin_amdgcn_global_load_lds(
        (const __attribute__((address_space(1))) void*)g,
        (__attribute__((address_space(3))) void*)l, 16, 0, 0);
}

__device__ __forceinline__ unsigned cvtpk(float lo, float hi) {
    unsigned r;
    asm("v_cvt_pk_bf16_f32 %0, %1, %2" : "=v"(r) : "v"(lo), "v"(hi));
    return r;
}

// ---------------------------------------------------------------------------
// Kernel 1: fused conv1x1 + PReLU producing Q,K (as [n][4096][32] bf16) and
// Vt (as [n][64][4096] bf16). Q pre-scaled by log2(e) so attn uses exp2.
// ---------------------------------------------------------------------------
__global__ __launch_bounds__(256, 2) void qkv_gen(
    const float* __restrict__ x,
    const float* __restrict__ w1, const float* __restrict__ b1, const float* __restrict__ a1,
    const float* __restrict__ w2, const float* __restrict__ b2, const float* __restrict__ a2,
    const float* __restrict__ w3, const float* __restrict__ b3, const float* __restrict__ a3,
    __bf16* __restrict__ qws, __bf16* __restrict__ kws, __bf16* __restrict__ vtws)
{
    __shared__ float xs[CIN][64];
    __shared__ float wl[CIN][128];
    __shared__ float bl[128];
    __shared__ float al[4];

    const int t  = threadIdx.x;
    const int n  = blockIdx.x >> 6;
    const int p0 = (blockIdx.x & 63) << 6;

    for (int idx = t; idx < 2048; idx += 256) {
        int j = idx >> 6, c = idx & 63;
        wl[c][j]      = w1[idx];
        wl[c][32 + j] = w2[idx];
    }
    for (int idx = t; idx < 4096; idx += 256) {
        int j = idx >> 6, c = idx & 63;
        wl[c][64 + j] = w3[idx];
    }
    if (t < 32) { bl[t] = b1[t]; bl[32 + t] = b2[t]; }
    if (t >= 128 && t < 192) bl[64 + (t - 128)] = b3[t - 128];
    if (t == 0) { al[0] = a1[0]; al[1] = a2[0]; al[2] = a3[0]; }

    const float* xb = x + ((size_t)n * CIN) * SEQ + p0;
    for (int r = 0; r < 16; ++r) {
        int e = r * 256 + t;
        xs[e >> 6][e & 63] = xb[(size_t)(e >> 6) * SEQ + (e & 63)];
    }
    __syncthreads();

    const int p  = t & 63;
    const int g  = t >> 6;
    const int jb = g << 5;
    const float a = (g == 0) ? al[0] : ((g == 1) ? al[1] : al[2]);

    float acc[32];
    #pragma unroll
    for (int j = 0; j < 32; ++j) acc[j] = bl[jb + j];

    for (int c = 0; c < CIN; ++c) {
        float xv = xs[c][p];
        const f32x4* wr = (const f32x4*)&wl[c][jb];
        #pragma unroll
        for (int j4 = 0; j4 < 8; ++j4) {
            f32x4 wv = wr[j4];
            acc[j4*4+0] = fmaf(wv[0], xv, acc[j4*4+0]);
            acc[j4*4+1] = fmaf(wv[1], xv, acc[j4*4+1]);
            acc[j4*4+2] = fmaf(wv[2], xv, acc[j4*4+2]);
            acc[j4*4+3] = fmaf(wv[3], xv, acc[j4*4+3]);
        }
    }
    #pragma unroll
    for (int j = 0; j < 32; ++j) acc[j] = acc[j] >= 0.f ? acc[j] : a * acc[j];

    const int pg = p0 + p;
    if (g <= 1) {
        const float sc = (g == 0) ? LOG2E : 1.0f;
        __bf16* dst = (g == 0 ? qws : kws) + ((size_t)n * SEQ + pg) * 32;
        #pragma unroll
        for (int v8 = 0; v8 < 4; ++v8) {
            bf16x8 o;
            #pragma unroll
            for (int i = 0; i < 8; ++i) o[i] = (__bf16)(acc[v8*8+i] * sc);
            *(bf16x8*)(dst + v8*8) = o;
        }
    } else {
        __bf16* dst = vtws + ((size_t)n * CIN + (jb - 64)) * SEQ + pg;
        #pragma unroll
        for (int j = 0; j < 32; ++j) dst[(size_t)j * SEQ] = (__bf16)acc[j];
    }
}

// ---------------------------------------------------------------------------
// Kernel 2: flash attention, 32x32 MFMA, in-register P, K-SPLIT=8 partials,
// 2-deep staging (24 KB LDS -> 6 blocks/CU = 24 waves/CU).
// Per iter: wait vmcnt(0) [stage(t) issued one compute-phase ago -> ~free]
//           -> s_barrier -> stage(t+1) -> compute(t).
// ATOMIC=0: bf16 partial O per ksplit slice + f32 l slice (plain stores).
// ATOMIC=1: f32 atomic fallback (small ws_size).
// ---------------------------------------------------------------------------
template<int ATOMIC>
__global__ __launch_bounds__(256, 6) void attn(
    const __bf16* __restrict__ qws, const __bf16* __restrict__ kws,
    const __bf16* __restrict__ vtws,
    void* __restrict__ Ows, float* __restrict__ lws)
{
    __shared__ __align__(16) char stg[2][12288];   // per stage: K @0 (4KB), V @4096 (8KB)

    const int t    = threadIdx.x;     // 256 threads, 4 waves
    const int lane = t & 63;
    const int n    = blockIdx.x & 7;
    const int qblk = (blockIdx.x >> 3) & 31;
    const int ks   = blockIdx.x >> 8;
    const int wid  = t >> 6;
    const int l31  = lane & 31;
    const int h    = lane >> 5;
    const int qbase = qblk * 128 + wid * 32;
    const int kbase = ks * KCHUNK;
    const int ksw  = ((l31 >> 1) & 3) << 4;
    const int vsw  = (l31 & 7) << 4;

    const char* kb = (const char*)(kws + (size_t)n * SEQ * 32);
    const char* vb = (const char*)(vtws + (size_t)n * CIN * SEQ);

    const char* qp = (const char*)(qws + (size_t)n * SEQ * 32)
                     + (size_t)(qbase + l31) * 64 + h * 16;
    const bf16x8 qf0 = *(const bf16x8*)(qp);
    const bf16x8 qf1 = *(const bf16x8*)(qp + 32);

    f32x16 of0 = {}, of1 = {};
    float ls = 0.f;

    auto stage = [&](int k0n, int b) {
        {
            int row = t >> 2;
            int c16 = (t & 3) ^ ((t >> 3) & 3);
            gll16(kb + (size_t)(k0n + row) * 64 + c16 * 16, &stg[b][0] + t * 16);
        }
        #pragma unroll
        for (int j = 0; j < 2; ++j) {
            int L   = j * 4096 + t * 16;
            int row = j * 32 + (t >> 3);
            int c16 = (t & 7) ^ ((t >> 3) & 7);
            gll16(vb + (size_t)row * 8192 + (size_t)k0n * 2 + c16 * 16,
                  &stg[b][4096] + L);
        }
    };

    stage(kbase, 0);

    int cur = 0;
    for (int tt = 0; tt < NTC; ++tt) {
        asm volatile("s_waitcnt vmcnt(0)" ::: "memory");   // stage(t) done (issued 1 phase ago)
        __builtin_amdgcn_s_barrier();                      // all waves done reading buf cur^1

        if (tt + 1 < NTC) stage(kbase + (tt + 1) * KBLK, cur ^ 1);

        const char* kc_ = &stg[cur][0];
        const char* vc_ = &stg[cur][4096];

        unsigned c0[8], c1[8];

        #pragma unroll
        for (int kti = 0; kti < 2; ++kti) {
            const char* krow = kc_ + (size_t)(kti * 32 + l31) * 64;
            bf16x8 kf0 = *(const bf16x8*)(krow + ((h * 16) ^ ksw));
            bf16x8 kf1 = *(const bf16x8*)(krow + ((32 + h * 16) ^ ksw));
            f32x16 s = {};
            __builtin_amdgcn_s_setprio(1);
            s = __builtin_amdgcn_mfma_f32_32x32x16_bf16(kf0, qf0, s, 0, 0, 0);
            s = __builtin_amdgcn_mfma_f32_32x32x16_bf16(kf1, qf1, s, 0, 0, 0);
            __builtin_amdgcn_s_setprio(0);

            float p[16];
            #pragma unroll
            for (int r = 0; r < 16; ++r) {
                p[r] = __builtin_exp2f(s[r]);
                ls += p[r];
            }
            unsigned* c = kti ? c1 : c0;
            #pragma unroll
            for (int j = 0; j < 4; ++j) {
                c[j]     = cvtpk(p[2*j],     p[2*j + 1]);
                c[4 + j] = cvtpk(p[8 + 2*j], p[9 + 2*j]);
            }
            asm("v_permlane32_swap_b32 %0, %1" : "+v"(c[0]), "+v"(c[2]));
            asm("v_permlane32_swap_b32 %0, %1" : "+v"(c[1]), "+v"(c[3]));
            asm("v_permlane32_swap_b32 %0, %1" : "+v"(c[4]), "+v"(c[6]));
            asm("v_permlane32_swap_b32 %0, %1" : "+v"(c[5]), "+v"(c[7]));
        }

        __builtin_amdgcn_s_setprio(1);
        #pragma unroll
        for (int s4 = 0; s4 < 4; ++s4) {
            const unsigned* cs = (s4 < 2) ? c0 : c1;
            const int sl = (s4 & 1) * 4;
            i32x4 bi = { (int)cs[sl], (int)cs[sl+1], (int)cs[sl+2], (int)cs[sl+3] };
            bf16x8 pf = __builtin_bit_cast(bf16x8, bi);
            const int colv = (s4 * 32 + h * 16) ^ vsw;
            bf16x8 vf0 = *(const bf16x8*)(vc_ + (size_t)l31 * 128 + colv);
            bf16x8 vf1 = *(const bf16x8*)(vc_ + (size_t)(32 + l31) * 128 + colv);
            of0 = __builtin_amdgcn_mfma_f32_32x32x16_bf16(vf0, pf, of0, 0, 0, 0);
            of1 = __builtin_amdgcn_mfma_f32_32x32x16_bf16(vf1, pf, of1, 0, 0, 0);
        }
        __builtin_amdgcn_s_setprio(0);

        cur ^= 1;
    }

    // ---- epilogue: partial O and l ----
    const int qg = qbase + l31;
    if (ATOMIC) {
        float* Ob = (float*)Ows + (size_t)n * CIN * SEQ;
        #pragma unroll
        for (int r = 0; r < 16; ++r) {
            int dv = (r & 3) + 8 * (r >> 2) + 4 * h;
            unsafeAtomicAdd(Ob + (size_t)dv * SEQ + qg,        of0[r]);
            unsafeAtomicAdd(Ob + (size_t)(dv + 32) * SEQ + qg, of1[r]);
        }
        unsafeAtomicAdd(lws + n * SEQ + qg, ls);
    } else {
        __bf16* Ob = (__bf16*)Ows + (size_t)ks * (8 * CIN * SEQ) + (size_t)n * CIN * SEQ;
        #pragma unroll
        for (int r = 0; r < 16; ++r) {
            int dv = (r & 3) + 8 * (r >> 2) + 4 * h;
            Ob[(size_t)dv * SEQ + qg]        = (__bf16)of0[r];
            Ob[(size_t)(dv + 32) * SEQ + qg] = (__bf16)of1[r];
        }
        float lt = ls + __shfl_xor(ls, 32);
        if (h == 0) lws[(size_t)ks * (8 * SEQ) + n * SEQ + qg] = lt;
    }
}

// ---------------------------------------------------------------------------
// Kernel 3a: lred — lws[0][n][q] := 1 / sum_ks lws[ks][n][q]   (in place)
// ---------------------------------------------------------------------------
__global__ __launch_bounds__(256) void lred(float* __restrict__ lws)
{
    int i = blockIdx.x * 256 + threadIdx.x;        // 32768 = 8n x 4096q
    float s = 0.f;
    #pragma unroll
    for (int ks = 0; ks < KSPLIT; ++ks) s += lws[ks * 32768 + i];
    lws[i] = 1.f / s;
}

// ---------------------------------------------------------------------------
// Kernel 3b: combine8 — out = (sum_ks O_ks) * linv + x   (bf16 partials)
// ---------------------------------------------------------------------------
__global__ __launch_bounds__(256) void combine8(
    const __bf16* __restrict__ O8, const float* __restrict__ linv,
    const float* __restrict__ x, float* __restrict__ out)
{
    const int i = blockIdx.x * 256 + threadIdx.x;  // 262144 slots of 8 outputs
    const int q8 = i & 511;
    const int nd = i >> 9;                          // n*64 + dv
    const int n  = nd >> 6;

    float o[8] = {};
    const __bf16* base = O8 + (size_t)nd * SEQ + q8 * 8;
    #pragma unroll
    for (int ks = 0; ks < KSPLIT; ++ks) {
        bf16x8 v = *(const bf16x8*)(base + (size_t)ks * (8 * CIN * SEQ));
        #pragma unroll
        for (int j = 0; j < 8; ++j) o[j] += (float)v[j];
    }
    const float* ivp = linv + n * SEQ + q8 * 8;
    f32x4 iv0 = *(const f32x4*)(ivp);
    f32x4 iv1 = *(const f32x4*)(ivp + 4);
    const float* xp = x + (size_t)nd * SEQ + q8 * 8;
    f32x4 x0 = *(const f32x4*)(xp);
    f32x4 x1 = *(const f32x4*)(xp + 4);
    f32x4 r0, r1;
    r0[0] = o[0]*iv0[0] + x0[0]; r0[1] = o[1]*iv0[1] + x0[1];
    r0[2] = o[2]*iv0[2] + x0[2]; r0[3] = o[3]*iv0[3] + x0[3];
    r1[0] = o[4]*iv1[0] + x1[0]; r1[1] = o[5]*iv1[1] + x1[1];
    r1[2] = o[6]*iv1[2] + x1[2]; r1[3] = o[7]*iv1[3] + x1[3];
    float* op = out + (size_t)nd * SEQ + q8 * 8;
    *(f32x4*)(op)     = r0;
    *(f32x4*)(op + 4) = r1;
}

// ---------------------------------------------------------------------------
// Kernel 3c: combine1 — legacy (atomic-accumulated f32 buffer)
// ---------------------------------------------------------------------------
__global__ __launch_bounds__(256) void combine1(
    const float* __restrict__ Ows, const float* __restrict__ lws,
    const float* __restrict__ x, float* __restrict__ out)
{
    const int total = 8 * CIN * SEQ / 4;
    for (int i = blockIdx.x * 256 + threadIdx.x; i < total; i += gridDim.x * 256) {
        int q4 = i & 1023;
        int n  = i >> 16;
        f32x4 o4 = *(const f32x4*)(Ows + (size_t)i * 4);
        f32x4 l4 = *(const f32x4*)(lws + (size_t)n * SEQ + q4 * 4);
        f32x4 x4 = *(const f32x4*)(x + (size_t)i * 4);
        f32x4 r;
        r[0] = o4[0] / l4[0] + x4[0];
        r[1] = o4[1] / l4[1] + x4[1];
        r[2] = o4[2] / l4[2] + x4[2];
        r[3] = o4[3] / l4[3] + x4[3];
        *(f32x4*)(out + (size_t)i * 4) = r;
    }
}

extern "C" void kernel_launch(void* const* d_in, const int* in_sizes, int n_in,
                              void* d_out, int out_size, void* d_ws, size_t ws_size,
                              hipStream_t stream)
{
    (void)in_sizes; (void)n_in; (void)out_size;
    const float* x  = (const float*)d_in[0];
    const float* w1 = (const float*)d_in[1];
    const float* b1 = (const float*)d_in[2];
    const float* a1 = (const float*)d_in[3];
    const float* w2 = (const float*)d_in[4];
    const float* b2 = (const float*)d_in[5];
    const float* a2 = (const float*)d_in[6];
    const float* w3 = (const float*)d_in[7];
    const float* b3 = (const float*)d_in[8];
    const float* a3 = (const float*)d_in[9];
    float* out = (float*)d_out;

    char* ws = (char*)d_ws;
    __bf16* qws  = (__bf16*)(ws);                        // 2 MB
    __bf16* kws  = (__bf16*)(ws + (2u << 20));           // 2 MB
    __bf16* vtws = (__bf16*)(ws + (4u << 20));           // 4 MB

    hipLaunchKernelGGL(qkv_gen, dim3(512), dim3(256), 0, stream,
                       x, w1, b1, a1, w2, b2, a2, w3, b3, a3, qws, kws, vtws);

    const size_t need_split = (8u << 20) + (32u << 20) + (1u << 20);
    if (ws_size >= need_split) {
        // bf16 split partials, no atomics, no memset
        __bf16* O8   = (__bf16*)(ws + (8u << 20));        // 32 MB [8ks][8n][64][4096]
        float*  lws8 = (float*)(ws + (40u << 20));        // 1 MB  [8ks][8n][4096]
        hipLaunchKernelGGL(attn<0>, dim3(8 * 32 * KSPLIT), dim3(256), 0, stream,
                           qws, kws, vtws, (void*)O8, lws8);
        hipLaunchKernelGGL(lred, dim3(128), dim3(256), 0, stream, lws8);
        hipLaunchKernelGGL(combine8, dim3(1024), dim3(256), 0, stream,
                           O8, lws8, x, out);
    } else {
        // legacy atomic fallback
        float* Ows = (float*)(ws + (8u << 20));           // 8 MB
        float* lws = (float*)(ws + (16u << 20));          // 128 KB
        hipMemsetAsync(Ows, 0, (8u << 20) + (128u << 10), stream);
        hipLaunchKernelGGL(attn<1>, dim3(8 * 32 * KSPLIT), dim3(256), 0, stream,
                           qws, kws, vtws, (void*)Ows, lws);
        hipLaunchKernelGGL(combine1, dim3(1024), dim3(256), 0, stream,
                           Ows, lws, x, out);
    }
}

// Round 10
// 82.801 us; speedup vs baseline: 2.9784x; 2.9784x over previous
//
#include <hip/hip_runtime.h>
#include <hip/hip_bf16.h>

typedef __bf16 bf16x8 __attribute__((ext_vector_type(8)));
typedef float  f32x4  __attribute__((ext_vector_type(4)));
typedef float  f32x16 __attribute__((ext_vector_type(16)));
typedef int    i32x4  __attribute__((ext_vector_type(4)));

#define SEQ 4096
#define CIN 64
#define KBLK 64
#define KSPLIT 8
#define KCHUNK (SEQ / KSPLIT)          // 512 keys per block
#define NTC (KCHUNK / KBLK)            // 8 iters
#define LOG2E 1.44269504088896340736f

__device__ __forceinline__ void gll16(const void* g, void* l) {
    __builtin_amdgcn_global_load_lds(
        (const __attribute__((address_space(1))) void*)g,
        (__attribute__((address_space(3))) void*)l, 16, 0, 0);
}

__device__ __forceinline__ unsigned cvtpk(float lo, float hi) {
    unsigned r;
    asm("v_cvt_pk_bf16_f32 %0, %1, %2" : "=v"(r) : "v"(lo), "v"(hi));
    return r;
}

// ---------------------------------------------------------------------------
// Kernel 1: fused conv1x1 + PReLU producing Q,K (as [n][4096][32] bf16) and
// Vt (as [n][64][4096] bf16). Q pre-scaled by log2(e) so attn uses exp2.
// ---------------------------------------------------------------------------
__global__ __launch_bounds__(256, 2) void qkv_gen(
    const float* __restrict__ x,
    const float* __restrict__ w1, const float* __restrict__ b1, const float* __restrict__ a1,
    const float* __restrict__ w2, const float* __restrict__ b2, const float* __restrict__ a2,
    const float* __restrict__ w3, const float* __restrict__ b3, const float* __restrict__ a3,
    __bf16* __restrict__ qws, __bf16* __restrict__ kws, __bf16* __restrict__ vtws)
{
    __shared__ float xs[CIN][64];
    __shared__ float wl[CIN][128];
    __shared__ float bl[128];
    __shared__ float al[4];

    const int t  = threadIdx.x;
    const int n  = blockIdx.x >> 6;
    const int p0 = (blockIdx.x & 63) << 6;

    for (int idx = t; idx < 2048; idx += 256) {
        int j = idx >> 6, c = idx & 63;
        wl[c][j]      = w1[idx];
        wl[c][32 + j] = w2[idx];
    }
    for (int idx = t; idx < 4096; idx += 256) {
        int j = idx >> 6, c = idx & 63;
        wl[c][64 + j] = w3[idx];
    }
    if (t < 32) { bl[t] = b1[t]; bl[32 + t] = b2[t]; }
    if (t >= 128 && t < 192) bl[64 + (t - 128)] = b3[t - 128];
    if (t == 0) { al[0] = a1[0]; al[1] = a2[0]; al[2] = a3[0]; }

    const float* xb = x + ((size_t)n * CIN) * SEQ + p0;
    for (int r = 0; r < 16; ++r) {
        int e = r * 256 + t;
        xs[e >> 6][e & 63] = xb[(size_t)(e >> 6) * SEQ + (e & 63)];
    }
    __syncthreads();

    const int p  = t & 63;
    const int g  = t >> 6;
    const int jb = g << 5;
    const float a = (g == 0) ? al[0] : ((g == 1) ? al[1] : al[2]);

    float acc[32];
    #pragma unroll
    for (int j = 0; j < 32; ++j) acc[j] = bl[jb + j];

    for (int c = 0; c < CIN; ++c) {
        float xv = xs[c][p];
        const f32x4* wr = (const f32x4*)&wl[c][jb];
        #pragma unroll
        for (int j4 = 0; j4 < 8; ++j4) {
            f32x4 wv = wr[j4];
            acc[j4*4+0] = fmaf(wv[0], xv, acc[j4*4+0]);
            acc[j4*4+1] = fmaf(wv[1], xv, acc[j4*4+1]);
            acc[j4*4+2] = fmaf(wv[2], xv, acc[j4*4+2]);
            acc[j4*4+3] = fmaf(wv[3], xv, acc[j4*4+3]);
        }
    }
    #pragma unroll
    for (int j = 0; j < 32; ++j) acc[j] = acc[j] >= 0.f ? acc[j] : a * acc[j];

    const int pg = p0 + p;
    if (g <= 1) {
        const float sc = (g == 0) ? LOG2E : 1.0f;
        __bf16* dst = (g == 0 ? qws : kws) + ((size_t)n * SEQ + pg) * 32;
        #pragma unroll
        for (int v8 = 0; v8 < 4; ++v8) {
            bf16x8 o;
            #pragma unroll
            for (int i = 0; i < 8; ++i) o[i] = (__bf16)(acc[v8*8+i] * sc);
            *(bf16x8*)(dst + v8*8) = o;
        }
    } else {
        __bf16* dst = vtws + ((size_t)n * CIN + (jb - 64)) * SEQ + pg;
        #pragma unroll
        for (int j = 0; j < 32; ++j) dst[(size_t)j * SEQ] = (__bf16)acc[j];
    }
}

// ---------------------------------------------------------------------------
// Kernel 2: flash attention, 32x32 MFMA, in-register P, K-SPLIT=8 partials,
// 2-deep staging (24 KB LDS -> 6 blocks/CU = 24 waves/CU).
// __launch_bounds__(256,4): r9's (256,6) squeezed VGPR to 40 and SPILLED
// accumulators to scratch (WRITE_SIZE 33->549 MB). (256,4) = proven 52-VGPR
// no-spill regime; LDS (not VGPR) then limits residency at 6 blocks/CU.
// ATOMIC=0: bf16 partial O per ksplit slice + f32 l slice (plain stores).
// ---------------------------------------------------------------------------
template<int ATOMIC>
__global__ __launch_bounds__(256, 4) void attn(
    const __bf16* __restrict__ qws, const __bf16* __restrict__ kws,
    const __bf16* __restrict__ vtws,
    void* __restrict__ Ows, float* __restrict__ lws)
{
    __shared__ __align__(16) char stg[2][12288];   // per stage: K @0 (4KB), V @4096 (8KB)

    const int t    = threadIdx.x;     // 256 threads, 4 waves
    const int lane = t & 63;
    const int n    = blockIdx.x & 7;
    const int qblk = (blockIdx.x >> 3) & 31;
    const int ks   = blockIdx.x >> 8;
    const int wid  = t >> 6;
    const int l31  = lane & 31;
    const int h    = lane >> 5;
    const int qbase = qblk * 128 + wid * 32;
    const int kbase = ks * KCHUNK;
    const int ksw  = ((l31 >> 1) & 3) << 4;
    const int vsw  = (l31 & 7) << 4;

    const char* kb = (const char*)(kws + (size_t)n * SEQ * 32);
    const char* vb = (const char*)(vtws + (size_t)n * CIN * SEQ);

    const char* qp = (const char*)(qws + (size_t)n * SEQ * 32)
                     + (size_t)(qbase + l31) * 64 + h * 16;
    const bf16x8 qf0 = *(const bf16x8*)(qp);
    const bf16x8 qf1 = *(const bf16x8*)(qp + 32);

    f32x16 of0 = {}, of1 = {};
    float ls = 0.f;

    auto stage = [&](int k0n, int b) {
        {
            int row = t >> 2;
            int c16 = (t & 3) ^ ((t >> 3) & 3);
            gll16(kb + (size_t)(k0n + row) * 64 + c16 * 16, &stg[b][0] + t * 16);
        }
        #pragma unroll
        for (int j = 0; j < 2; ++j) {
            int L   = j * 4096 + t * 16;
            int row = j * 32 + (t >> 3);
            int c16 = (t & 7) ^ ((t >> 3) & 7);
            gll16(vb + (size_t)row * 8192 + (size_t)k0n * 2 + c16 * 16,
                  &stg[b][4096] + L);
        }
    };

    stage(kbase, 0);

    int cur = 0;
    for (int tt = 0; tt < NTC; ++tt) {
        asm volatile("s_waitcnt vmcnt(0)" ::: "memory");   // stage(t) done (issued 1 phase ago)
        __builtin_amdgcn_s_barrier();                      // all waves done reading buf cur^1

        if (tt + 1 < NTC) stage(kbase + (tt + 1) * KBLK, cur ^ 1);

        const char* kc_ = &stg[cur][0];
        const char* vc_ = &stg[cur][4096];

        unsigned c0[8], c1[8];

        #pragma unroll
        for (int kti = 0; kti < 2; ++kti) {
            const char* krow = kc_ + (size_t)(kti * 32 + l31) * 64;
            bf16x8 kf0 = *(const bf16x8*)(krow + ((h * 16) ^ ksw));
            bf16x8 kf1 = *(const bf16x8*)(krow + ((32 + h * 16) ^ ksw));
            f32x16 s = {};
            __builtin_amdgcn_s_setprio(1);
            s = __builtin_amdgcn_mfma_f32_32x32x16_bf16(kf0, qf0, s, 0, 0, 0);
            s = __builtin_amdgcn_mfma_f32_32x32x16_bf16(kf1, qf1, s, 0, 0, 0);
            __builtin_amdgcn_s_setprio(0);

            float p[16];
            #pragma unroll
            for (int r = 0; r < 16; ++r) {
                p[r] = __builtin_exp2f(s[r]);
                ls += p[r];
            }
            unsigned* c = kti ? c1 : c0;
            #pragma unroll
            for (int j = 0; j < 4; ++j) {
                c[j]     = cvtpk(p[2*j],     p[2*j + 1]);
                c[4 + j] = cvtpk(p[8 + 2*j], p[9 + 2*j]);
            }
            asm("v_permlane32_swap_b32 %0, %1" : "+v"(c[0]), "+v"(c[2]));
            asm("v_permlane32_swap_b32 %0, %1" : "+v"(c[1]), "+v"(c[3]));
            asm("v_permlane32_swap_b32 %0, %1" : "+v"(c[4]), "+v"(c[6]));
            asm("v_permlane32_swap_b32 %0, %1" : "+v"(c[5]), "+v"(c[7]));
        }

        __builtin_amdgcn_s_setprio(1);
        #pragma unroll
        for (int s4 = 0; s4 < 4; ++s4) {
            const unsigned* cs = (s4 < 2) ? c0 : c1;
            const int sl = (s4 & 1) * 4;
            i32x4 bi = { (int)cs[sl], (int)cs[sl+1], (int)cs[sl+2], (int)cs[sl+3] };
            bf16x8 pf = __builtin_bit_cast(bf16x8, bi);
            const int colv = (s4 * 32 + h * 16) ^ vsw;
            bf16x8 vf0 = *(const bf16x8*)(vc_ + (size_t)l31 * 128 + colv);
            bf16x8 vf1 = *(const bf16x8*)(vc_ + (size_t)(32 + l31) * 128 + colv);
            of0 = __builtin_amdgcn_mfma_f32_32x32x16_bf16(vf0, pf, of0, 0, 0, 0);
            of1 = __builtin_amdgcn_mfma_f32_32x32x16_bf16(vf1, pf, of1, 0, 0, 0);
        }
        __builtin_amdgcn_s_setprio(0);

        cur ^= 1;
    }

    // ---- epilogue: partial O and l ----
    const int qg = qbase + l31;
    if (ATOMIC) {
        float* Ob = (float*)Ows + (size_t)n * CIN * SEQ;
        #pragma unroll
        for (int r = 0; r < 16; ++r) {
            int dv = (r & 3) + 8 * (r >> 2) + 4 * h;
            unsafeAtomicAdd(Ob + (size_t)dv * SEQ + qg,        of0[r]);
            unsafeAtomicAdd(Ob + (size_t)(dv + 32) * SEQ + qg, of1[r]);
        }
        unsafeAtomicAdd(lws + n * SEQ + qg, ls);
    } else {
        __bf16* Ob = (__bf16*)Ows + (size_t)ks * (8 * CIN * SEQ) + (size_t)n * CIN * SEQ;
        #pragma unroll
        for (int r = 0; r < 16; ++r) {
            int dv = (r & 3) + 8 * (r >> 2) + 4 * h;
            Ob[(size_t)dv * SEQ + qg]        = (__bf16)of0[r];
            Ob[(size_t)(dv + 32) * SEQ + qg] = (__bf16)of1[r];
        }
        float lt = ls + __shfl_xor(ls, 32);
        if (h == 0) lws[(size_t)ks * (8 * SEQ) + n * SEQ + qg] = lt;
    }
}

// ---------------------------------------------------------------------------
// Kernel 3a: lred — lws[0][n][q] := 1 / sum_ks lws[ks][n][q]   (in place)
// ---------------------------------------------------------------------------
__global__ __launch_bounds__(256) void lred(float* __restrict__ lws)
{
    int i = blockIdx.x * 256 + threadIdx.x;        // 32768 = 8n x 4096q
    float s = 0.f;
    #pragma unroll
    for (int ks = 0; ks < KSPLIT; ++ks) s += lws[ks * 32768 + i];
    lws[i] = 1.f / s;
}

// ---------------------------------------------------------------------------
// Kernel 3b: combine8 — out = (sum_ks O_ks) * linv + x   (bf16 partials)
// ---------------------------------------------------------------------------
__global__ __launch_bounds__(256) void combine8(
    const __bf16* __restrict__ O8, const float* __restrict__ linv,
    const float* __restrict__ x, float* __restrict__ out)
{
    const int i = blockIdx.x * 256 + threadIdx.x;  // 262144 slots of 8 outputs
    const int q8 = i & 511;
    const int nd = i >> 9;                          // n*64 + dv
    const int n  = nd >> 6;

    float o[8] = {};
    const __bf16* base = O8 + (size_t)nd * SEQ + q8 * 8;
    #pragma unroll
    for (int ks = 0; ks < KSPLIT; ++ks) {
        bf16x8 v = *(const bf16x8*)(base + (size_t)ks * (8 * CIN * SEQ));
        #pragma unroll
        for (int j = 0; j < 8; ++j) o[j] += (float)v[j];
    }
    const float* ivp = linv + n * SEQ + q8 * 8;
    f32x4 iv0 = *(const f32x4*)(ivp);
    f32x4 iv1 = *(const f32x4*)(ivp + 4);
    const float* xp = x + (size_t)nd * SEQ + q8 * 8;
    f32x4 x0 = *(const f32x4*)(xp);
    f32x4 x1 = *(const f32x4*)(xp + 4);
    f32x4 r0, r1;
    r0[0] = o[0]*iv0[0] + x0[0]; r0[1] = o[1]*iv0[1] + x0[1];
    r0[2] = o[2]*iv0[2] + x0[2]; r0[3] = o[3]*iv0[3] + x0[3];
    r1[0] = o[4]*iv1[0] + x1[0]; r1[1] = o[5]*iv1[1] + x1[1];
    r1[2] = o[6]*iv1[2] + x1[2]; r1[3] = o[7]*iv1[3] + x1[3];
    float* op = out + (size_t)nd * SEQ + q8 * 8;
    *(f32x4*)(op)     = r0;
    *(f32x4*)(op + 4) = r1;
}

// ---------------------------------------------------------------------------
// Kernel 3c: combine1 — legacy (atomic-accumulated f32 buffer)
// ---------------------------------------------------------------------------
__global__ __launch_bounds__(256) void combine1(
    const float* __restrict__ Ows, const float* __restrict__ lws,
    const float* __restrict__ x, float* __restrict__ out)
{
    const int total = 8 * CIN * SEQ / 4;
    for (int i = blockIdx.x * 256 + threadIdx.x; i < total; i += gridDim.x * 256) {
        int q4 = i & 1023;
        int n  = i >> 16;
        f32x4 o4 = *(const f32x4*)(Ows + (size_t)i * 4);
        f32x4 l4 = *(const f32x4*)(lws + (size_t)n * SEQ + q4 * 4);
        f32x4 x4 = *(const f32x4*)(x + (size_t)i * 4);
        f32x4 r;
        r[0] = o4[0] / l4[0] + x4[0];
        r[1] = o4[1] / l4[1] + x4[1];
        r[2] = o4[2] / l4[2] + x4[2];
        r[3] = o4[3] / l4[3] + x4[3];
        *(f32x4*)(out + (size_t)i * 4) = r;
    }
}

extern "C" void kernel_launch(void* const* d_in, const int* in_sizes, int n_in,
                              void* d_out, int out_size, void* d_ws, size_t ws_size,
                              hipStream_t stream)
{
    (void)in_sizes; (void)n_in; (void)out_size;
    const float* x  = (const float*)d_in[0];
    const float* w1 = (const float*)d_in[1];
    const float* b1 = (const float*)d_in[2];
    const float* a1 = (const float*)d_in[3];
    const float* w2 = (const float*)d_in[4];
    const float* b2 = (const float*)d_in[5];
    const float* a2 = (const float*)d_in[6];
    const float* w3 = (const float*)d_in[7];
    const float* b3 = (const float*)d_in[8];
    const float* a3 = (const float*)d_in[9];
    float* out = (float*)d_out;

    char* ws = (char*)d_ws;
    __bf16* qws  = (__bf16*)(ws);                        // 2 MB
    __bf16* kws  = (__bf16*)(ws + (2u << 20));           // 2 MB
    __bf16* vtws = (__bf16*)(ws + (4u << 20));           // 4 MB

    hipLaunchKernelGGL(qkv_gen, dim3(512), dim3(256), 0, stream,
                       x, w1, b1, a1, w2, b2, a2, w3, b3, a3, qws, kws, vtws);

    const size_t need_split = (8u << 20) + (32u << 20) + (1u << 20);
    if (ws_size >= need_split) {
        // bf16 split partials, no atomics, no memset
        __bf16* O8   = (__bf16*)(ws + (8u << 20));        // 32 MB [8ks][8n][64][4096]
        float*  lws8 = (float*)(ws + (40u << 20));        // 1 MB  [8ks][8n][4096]
        hipLaunchKernelGGL(attn<0>, dim3(8 * 32 * KSPLIT), dim3(256), 0, stream,
                           qws, kws, vtws, (void*)O8, lws8);
        hipLaunchKernelGGL(lred, dim3(128), dim3(256), 0, stream, lws8);
        hipLaunchKernelGGL(combine8, dim3(1024), dim3(256), 0, stream,
                           O8, lws8, x, out);
    } else {
        // legacy atomic fallback
        float* Ows = (float*)(ws + (8u << 20));           // 8 MB
        float* lws = (float*)(ws + (16u << 20));          // 128 KB
        hipMemsetAsync(Ows, 0, (8u << 20) + (128u << 10), stream);
        hipLaunchKernelGGL(attn<1>, dim3(8 * 32 * KSPLIT), dim3(256), 0, stream,
                           qws, kws, vtws, (void*)Ows, lws);
        hipLaunchKernelGGL(combine1, dim3(1024), dim3(256), 0, stream,
                           Ows, lws, x, out);
    }
}